// Round 3
// baseline (1110.948 us; speedup 1.0000x reference)
//
#include <hip/hip_runtime.h>
#include <math.h>

#define HID 2048
#define NH 16
#define HD 128
#define INTER 8192
#define BB 2
#define SS 2048
#define MT (BB*SS)

typedef __bf16 bf16x8 __attribute__((ext_vector_type(8)));
typedef float f32x4 __attribute__((ext_vector_type(4)));
typedef unsigned short u16x8 __attribute__((ext_vector_type(8)));

__device__ __forceinline__ float bf2f(unsigned short u) {
  unsigned v = ((unsigned)u) << 16;
  return __builtin_bit_cast(float, v);
}
__device__ __forceinline__ unsigned short f2bf(float x) {
  unsigned u = __builtin_bit_cast(unsigned, x);
  u += 0x7fffu + ((u >> 16) & 1u);
  return (unsigned short)(u >> 16);
}
__device__ __forceinline__ void gll16(const void* g, const void* lds) {
  __builtin_amdgcn_global_load_lds(
      (const __attribute__((address_space(1))) void*)g,
      (__attribute__((address_space(3))) void*)lds, 16, 0, 0);
}

// ---------------- fused LayerNorm: x1 as hi/lo split, x2 plain bf16 --------
__global__ __launch_bounds__(256) void ln2k(
    const float* __restrict__ X, const float* __restrict__ s1,
    const float* __restrict__ b1, const float* __restrict__ s2,
    const float* __restrict__ b2, unsigned short* __restrict__ X1h,
    unsigned short* __restrict__ X1l, unsigned short* __restrict__ X2) {
  const int row = blockIdx.x;
  const int tid = threadIdx.x;
  const float* x = X + (long)row * HID;
  float4 v0 = ((const float4*)x)[tid * 2];
  float4 v1 = ((const float4*)x)[tid * 2 + 1];
  float s = v0.x + v0.y + v0.z + v0.w + v1.x + v1.y + v1.z + v1.w;
  float q = v0.x * v0.x + v0.y * v0.y + v0.z * v0.z + v0.w * v0.w +
            v1.x * v1.x + v1.y * v1.y + v1.z * v1.z + v1.w * v1.w;
#pragma unroll
  for (int off = 1; off < 64; off <<= 1) {
    s += __shfl_xor(s, off);
    q += __shfl_xor(q, off);
  }
  __shared__ float rs[4], rq[4];
  const int wid = tid >> 6, lane = tid & 63;
  if (lane == 0) { rs[wid] = s; rq[wid] = q; }
  __syncthreads();
  s = rs[0] + rs[1] + rs[2] + rs[3];
  q = rq[0] + rq[1] + rq[2] + rq[3];
  const float mu = s * (1.f / HID);
  const float var = q * (1.f / HID) - mu * mu;
  const float rstd = rsqrtf(var + 1e-5f);
  float xv[8] = {v0.x, v0.y, v0.z, v0.w, v1.x, v1.y, v1.z, v1.w};
  u16x8 o1h, o1l, o2;
#pragma unroll
  for (int e = 0; e < 8; e++) {
    const int j = tid * 8 + e;
    const float xn = (xv[e] - mu) * rstd;
    const float x1v = xn * s1[j] + b1[j];
    const unsigned short h = f2bf(x1v);
    o1h[e] = h;
    o1l[e] = f2bf(x1v - bf2f(h));
    o2[e] = f2bf(xn * s2[j] + b2[j]);
  }
  *(u16x8*)(X1h + (long)row * HID + tid * 8) = o1h;
  *(u16x8*)(X1l + (long)row * HID + tid * 8) = o1l;
  *(u16x8*)(X2 + (long)row * HID + tid * 8) = o2;
}

// ------- weight transpose + f32->bf16: W[k][ldn] cols [coff,coff+N) -------
__global__ __launch_bounds__(256) void wtrans(const float* __restrict__ W,
                                              unsigned short* __restrict__ WT,
                                              int K, int N, int ldn, int coff) {
  (void)N;
  __shared__ float t[32][33];
  const int n0 = blockIdx.x * 32, k0 = blockIdx.y * 32;
  const int tx = threadIdx.x, ty = threadIdx.y;
#pragma unroll
  for (int r = 0; r < 4; r++)
    t[ty + r * 8][tx] = W[(long)(k0 + ty + r * 8) * ldn + coff + n0 + tx];
  __syncthreads();
#pragma unroll
  for (int r = 0; r < 4; r++)
    WT[(long)(n0 + ty + r * 8) * K + k0 + tx] = f2bf(t[tx][ty + r * 8]);
}

// ------- same but hi/lo split output (for the q,k half of w_qkv) ----------
__global__ __launch_bounds__(256) void wtrans_hl(
    const float* __restrict__ W, unsigned short* __restrict__ WTh,
    unsigned short* __restrict__ WTl, int K, int ldn) {
  __shared__ float t[32][33];
  const int n0 = blockIdx.x * 32, k0 = blockIdx.y * 32;
  const int tx = threadIdx.x, ty = threadIdx.y;
#pragma unroll
  for (int r = 0; r < 4; r++)
    t[ty + r * 8][tx] = W[(long)(k0 + ty + r * 8) * ldn + n0 + tx];
  __syncthreads();
#pragma unroll
  for (int r = 0; r < 4; r++) {
    const float v = t[tx][ty + r * 8];
    const unsigned short h = f2bf(v);
    const long o = (long)(n0 + ty + r * 8) * K + k0 + tx;
    WTh[o] = h;
    WTl[o] = f2bf(v - bf2f(h));
  }
}

// ---------------- rope cos/sin table (f64 angle for accuracy) --------------
__global__ void rope_tab(float2* __restrict__ rope) {
  const int s = blockIdx.x, i = threadIdx.x;  // 2048 x 64
  const double ang = (double)s * pow(10000.0, -(double)i / 64.0);
  rope[s * 64 + i] = make_float2((float)cos(ang), (float)sin(ang));
}

// ---- split-precision GEMM for q,k (3-MFMA bf16 split) + fused RoPE -------
// C[M=4096][N=4096] = (Ah+Al)[M][K] @ (Bh+Bl)[N][K]^T + bias; epilogue
// rotates adjacent col pairs and writes hi/lo bf16 to QH/QL or KH/KL
// in [bh][s][128] layout.
__global__ __launch_bounds__(256) void gemmqk(
    const unsigned short* __restrict__ Ah_, const unsigned short* __restrict__ Al_,
    const unsigned short* __restrict__ Bh_, const unsigned short* __restrict__ Bl_,
    const float* __restrict__ bias, const float2* __restrict__ rope,
    unsigned short* __restrict__ QH, unsigned short* __restrict__ QL,
    unsigned short* __restrict__ KH, unsigned short* __restrict__ KL) {
  __shared__ unsigned short Ash[128 * 64], Asl[128 * 64];
  __shared__ unsigned short Bsh[128 * 64], Bsl[128 * 64];
  const int K = HID;
  const int tid = threadIdx.x;
  const int wid = tid >> 6, lane = tid & 63;
  const int l16 = lane & 15, lhi = lane >> 4;
  const int bn = blockIdx.x, bm = blockIdx.y;
  const int wr = wid >> 1, wc = wid & 1;
  const long rA0 = (long)bm * 128;
  const long rB0 = (long)bn * 128;

  f32x4 acc[4][4] = {};

  for (int kt = 0; kt < K; kt += 64) {
#pragma unroll
    for (int i = 0; i < 4; i++) {
      const int lin = i * 4096 + wid * 1024 + (lane << 4);
      const int row = lin >> 7;
      const int cs = ((lin >> 4) & 7) ^ (row & 7);
      const int dst = i * 4096 + wid * 1024;
      const long ga = (rA0 + row) * (long)K + kt + cs * 8;
      const long gb = (rB0 + row) * (long)K + kt + cs * 8;
      gll16(Ah_ + ga, (const char*)Ash + dst);
      gll16(Al_ + ga, (const char*)Asl + dst);
      gll16(Bh_ + gb, (const char*)Bsh + dst);
      gll16(Bl_ + gb, (const char*)Bsl + dst);
    }
    __syncthreads();
#pragma unroll
    for (int ks = 0; ks < 2; ks++) {
      bf16x8 avh[4], avl[4], bvh[4], bvl[4];
#pragma unroll
      for (int m = 0; m < 4; m++) {
        const int row = wr * 64 + m * 16 + l16;
        const int ch = (ks * 4 + lhi) ^ (row & 7);
        avh[m] = *(const bf16x8*)((const char*)Ash + row * 128 + ch * 16);
        avl[m] = *(const bf16x8*)((const char*)Asl + row * 128 + ch * 16);
      }
#pragma unroll
      for (int n = 0; n < 4; n++) {
        const int row = wc * 64 + n * 16 + l16;
        const int ch = (ks * 4 + lhi) ^ (row & 7);
        bvh[n] = *(const bf16x8*)((const char*)Bsh + row * 128 + ch * 16);
        bvl[n] = *(const bf16x8*)((const char*)Bsl + row * 128 + ch * 16);
      }
#pragma unroll
      for (int m = 0; m < 4; m++)
#pragma unroll
        for (int n = 0; n < 4; n++) {
          acc[m][n] = __builtin_amdgcn_mfma_f32_16x16x32_bf16(avh[m], bvl[n],
                                                              acc[m][n], 0, 0, 0);
          acc[m][n] = __builtin_amdgcn_mfma_f32_16x16x32_bf16(avl[m], bvh[n],
                                                              acc[m][n], 0, 0, 0);
          acc[m][n] = __builtin_amdgcn_mfma_f32_16x16x32_bf16(avh[m], bvh[n],
                                                              acc[m][n], 0, 0, 0);
        }
    }
    __syncthreads();
  }

  // epilogue: bias, RoPE pair rotation via shfl_xor(1), hi/lo split store
  const int b_ = (int)(rA0 >> 11);
#pragma unroll
  for (int m = 0; m < 4; m++) {
#pragma unroll
    for (int n = 0; n < 4; n++) {
      const int col = (int)rB0 + wc * 64 + n * 16 + l16;
      const float bsv = bias[col];
      const int i = (col & 127) >> 1;
      const int hh = (col >> 7) & 15;
      const int d = col & 127;
#pragma unroll
      for (int r = 0; r < 4; r++) {
        const int row = (int)rA0 + wr * 64 + m * 16 + lhi * 4 + r;
        const int srow = row & 2047;
        const float v = acc[m][n][r] + bsv;
        const float p = __shfl_xor(v, 1);
        const float2 cs = rope[srow * 64 + i];
        const float o = ((lane & 1) == 0) ? (v * cs.x - p * cs.y)
                                          : (p * cs.y + v * cs.x);
        const unsigned short hi = f2bf(o);
        const unsigned short lo = f2bf(o - bf2f(hi));
        const long dst = ((long)(b_ * NH + hh) * SS + srow) * HD + d;
        if (col < 2048) { QH[dst] = hi; QL[dst] = lo; }
        else            { KH[dst] = hi; KL[dst] = lo; }
      }
    }
  }
}

// ---------------- V transpose: Vbf [m][2048] -> VT [bh][128][s] ------------
__global__ __launch_bounds__(256) void vtrans(
    const unsigned short* __restrict__ Vb, unsigned short* __restrict__ VTb) {
  __shared__ unsigned short t[32][33];
  const int bh = blockIdx.z, b = bh >> 4, h = bh & 15;
  const int d0 = blockIdx.x * 32, s0 = blockIdx.y * 32;
  const int tx = threadIdx.x, ty = threadIdx.y;
#pragma unroll
  for (int r = 0; r < 4; r++) {
    const int s = s0 + ty + r * 8;
    t[ty + r * 8][tx] = Vb[((long)(b * SS + s)) * HID + h * HD + d0 + tx];
  }
  __syncthreads();
#pragma unroll
  for (int r = 0; r < 4; r++) {
    const int d = d0 + ty + r * 8;
    VTb[((long)bh * HD + d) * SS + s0 + tx] = t[tx][ty + r * 8];
  }
}

// ---------------- 128x128-tile plain bf16 GEMM ----------------
// MODE 0: bf16 out; 1: gelu+bf16; 2: +residF(f32)+residB(bf16), f32 out.
template <int MODE>
__global__ __launch_bounds__(256) void gemm128(
    const unsigned short* __restrict__ A, const unsigned short* __restrict__ Bt,
    const float* __restrict__ bias, void* __restrict__ Cout, int M, int N,
    int K, const float* __restrict__ residF,
    const unsigned short* __restrict__ residB) {
  (void)M;
  __shared__ unsigned short As[128 * 64];
  __shared__ unsigned short Bs[128 * 64];
  const int tid = threadIdx.x;
  const int wid = tid >> 6, lane = tid & 63;
  const int l16 = lane & 15, lhi = lane >> 4;
  const int bn = blockIdx.x, bm = blockIdx.y;
  const int wr = wid >> 1, wc = wid & 1;
  const long rA0 = (long)bm * 128;
  const long rB0 = (long)bn * 128;

  f32x4 acc[4][4] = {};

  for (int kt = 0; kt < K; kt += 64) {
#pragma unroll
    for (int i = 0; i < 4; i++) {
      const int lin = i * 4096 + wid * 1024 + (lane << 4);
      const int row = lin >> 7;
      const int cs = ((lin >> 4) & 7) ^ (row & 7);
      gll16(A + (rA0 + row) * (long)K + kt + cs * 8,
            (const char*)As + (i * 4096 + wid * 1024));
      gll16(Bt + (rB0 + row) * (long)K + kt + cs * 8,
            (const char*)Bs + (i * 4096 + wid * 1024));
    }
    __syncthreads();
#pragma unroll
    for (int ks = 0; ks < 2; ks++) {
      bf16x8 av[4], bv[4];
#pragma unroll
      for (int m = 0; m < 4; m++) {
        const int row = wr * 64 + m * 16 + l16;
        const int ch = (ks * 4 + lhi) ^ (row & 7);
        av[m] = *(const bf16x8*)((const char*)As + row * 128 + ch * 16);
      }
#pragma unroll
      for (int n = 0; n < 4; n++) {
        const int row = wc * 64 + n * 16 + l16;
        const int ch = (ks * 4 + lhi) ^ (row & 7);
        bv[n] = *(const bf16x8*)((const char*)Bs + row * 128 + ch * 16);
      }
#pragma unroll
      for (int m = 0; m < 4; m++)
#pragma unroll
        for (int n = 0; n < 4; n++)
          acc[m][n] = __builtin_amdgcn_mfma_f32_16x16x32_bf16(av[m], bv[n],
                                                              acc[m][n], 0, 0, 0);
    }
    __syncthreads();
  }

#pragma unroll
  for (int m = 0; m < 4; m++) {
#pragma unroll
    for (int n = 0; n < 4; n++) {
      const long col = rB0 + wc * 64 + n * 16 + l16;
      const float bsv = bias[col];
#pragma unroll
      for (int r = 0; r < 4; r++) {
        const long row = rA0 + wr * 64 + m * 16 + lhi * 4 + r;
        float v = acc[m][n][r] + bsv;
        if (MODE == 1) v = 0.5f * v * (1.f + erff(v * 0.7071067811865475f));
        if (MODE == 2) {
          v += residF[row * N + col] + bf2f(residB[row * N + col]);
          ((float*)Cout)[row * N + col] = v;
        } else {
          ((unsigned short*)Cout)[row * N + col] = f2bf(v);
        }
      }
    }
  }
}

// ---------------- flash attention with split-precision QK^T ----------------
// QH/QL/KH/KL: [bh][s][128]; VT: [bh][128][s]; AO: [b][s][h*128+d] bf16
__global__ __launch_bounds__(256) void flash(
    const unsigned short* __restrict__ QH, const unsigned short* __restrict__ QL,
    const unsigned short* __restrict__ KH, const unsigned short* __restrict__ KL,
    const unsigned short* __restrict__ VT, const float* __restrict__ amask,
    unsigned short* __restrict__ AO) {
  __shared__ unsigned short Kth[64 * 128];  // [key][d] hi
  __shared__ unsigned short Ktl[64 * 128];  // [key][d] lo
  __shared__ unsigned short Vt[128 * 64];   // [d][key]
  __shared__ unsigned short Pl[4 * 2048];   // per-wave 32x64 P
  const int qt = gridDim.x - 1 - blockIdx.x;
  const int bh = blockIdx.y;
  const int b = bh >> 4, h = bh & 15;
  const int tid = threadIdx.x, wid = tid >> 6, lane = tid & 63;
  const int l16 = lane & 15, lhi = lane >> 4;
  const unsigned short* Qhb = QH + (long)bh * SS * HD;
  const unsigned short* Qlb = QL + (long)bh * SS * HD;
  const unsigned short* Khb = KH + (long)bh * SS * HD;
  const unsigned short* Klb = KL + (long)bh * SS * HD;
  const unsigned short* Vb = VT + (long)bh * HD * SS;
  const int q0 = qt * 128 + wid * 32;

  bf16x8 qfh[2][4], qfl[2][4];
#pragma unroll
  for (int mf = 0; mf < 2; mf++)
#pragma unroll
    for (int ks = 0; ks < 4; ks++) {
      const long o = (long)(q0 + mf * 16 + l16) * HD + ks * 32 + lhi * 8;
      qfh[mf][ks] = *(const bf16x8*)(Qhb + o);
      qfl[mf][ks] = *(const bf16x8*)(Qlb + o);
    }

  f32x4 accO[2][8] = {};
  float mrow[2][4], lrow[2][4];
#pragma unroll
  for (int mf = 0; mf < 2; mf++)
#pragma unroll
    for (int r = 0; r < 4; r++) { mrow[mf][r] = -3e38f; lrow[mf][r] = 0.f; }

  const int nkt = 2 * qt + 2;
  for (int kt = 0; kt < nkt; kt++) {
#pragma unroll
    for (int i = 0; i < 4; i++) {
      const int lin = i * 4096 + wid * 1024 + (lane << 4);
      const int dst = i * 4096 + wid * 1024;
      {
        const int row = lin >> 8;
        const int cs = ((lin >> 4) & 15) ^ (row & 7);
        const long g = (long)(kt * 64 + row) * HD + cs * 8;
        gll16(Khb + g, (const char*)Kth + dst);
        gll16(Klb + g, (const char*)Ktl + dst);
      }
      {
        const int row = lin >> 7;
        const int cs = ((lin >> 4) & 7) ^ (row & 7);
        gll16(Vb + (long)row * SS + kt * 64 + cs * 8, (const char*)Vt + dst);
      }
    }
    __syncthreads();

    // S = (Qh+Ql)(Kh+Kl)^T  (3-term split)
    f32x4 accS[2][4] = {};
#pragma unroll
    for (int ks = 0; ks < 4; ks++) {
      bf16x8 bkh[4], bkl[4];
#pragma unroll
      for (int nf = 0; nf < 4; nf++) {
        const int row = nf * 16 + l16;
        const int ch = (ks * 4 + lhi) ^ (row & 7);
        bkh[nf] = *(const bf16x8*)((const char*)Kth + row * 256 + ch * 16);
        bkl[nf] = *(const bf16x8*)((const char*)Ktl + row * 256 + ch * 16);
      }
#pragma unroll
      for (int mf = 0; mf < 2; mf++)
#pragma unroll
        for (int nf = 0; nf < 4; nf++) {
          accS[mf][nf] = __builtin_amdgcn_mfma_f32_16x16x32_bf16(
              qfh[mf][ks], bkl[nf], accS[mf][nf], 0, 0, 0);
          accS[mf][nf] = __builtin_amdgcn_mfma_f32_16x16x32_bf16(
              qfl[mf][ks], bkh[nf], accS[mf][nf], 0, 0, 0);
          accS[mf][nf] = __builtin_amdgcn_mfma_f32_16x16x32_bf16(
              qfh[mf][ks], bkh[nf], accS[mf][nf], 0, 0, 0);
        }
    }

    // scale * sqrt(128) + mask + causal
#pragma unroll
    for (int mf = 0; mf < 2; mf++)
#pragma unroll
      for (int nf = 0; nf < 4; nf++)
#pragma unroll
        for (int r = 0; r < 4; r++) {
          const int key = kt * 64 + nf * 16 + l16;
          const int qg = q0 + mf * 16 + lhi * 4 + r;
          float sv = accS[mf][nf][r] * 11.313708498984761f +
                     amask[b * SS + key];
          accS[mf][nf][r] = (key > qg) ? -1e30f : sv;
        }

    // online softmax, write P (bf16) to per-wave LDS
#pragma unroll
    for (int mf = 0; mf < 2; mf++)
#pragma unroll
      for (int r = 0; r < 4; r++) {
        float mx = fmaxf(fmaxf(accS[mf][0][r], accS[mf][1][r]),
                         fmaxf(accS[mf][2][r], accS[mf][3][r]));
        mx = fmaxf(mx, __shfl_xor(mx, 1));
        mx = fmaxf(mx, __shfl_xor(mx, 2));
        mx = fmaxf(mx, __shfl_xor(mx, 4));
        mx = fmaxf(mx, __shfl_xor(mx, 8));
        const float mnew = fmaxf(mrow[mf][r], mx);
        const float alpha = expf(mrow[mf][r] - mnew);
        mrow[mf][r] = mnew;
        const int rowl = mf * 16 + lhi * 4 + r;
        const int qg = q0 + rowl;
        float rsum = 0.f;
#pragma unroll
        for (int nf = 0; nf < 4; nf++) {
          const int key = kt * 64 + nf * 16 + l16;
          const float p = (key > qg) ? 0.f : expf(accS[mf][nf][r] - mnew);
          rsum += p;
          const int colv = nf * 16 + l16;
          const int slot = (colv >> 3) ^ (rowl & 7);
          Pl[wid * 2048 + rowl * 64 + slot * 8 + (colv & 7)] = f2bf(p);
        }
        rsum += __shfl_xor(rsum, 1);
        rsum += __shfl_xor(rsum, 2);
        rsum += __shfl_xor(rsum, 4);
        rsum += __shfl_xor(rsum, 8);
        lrow[mf][r] = lrow[mf][r] * alpha + rsum;
#pragma unroll
        for (int nf2 = 0; nf2 < 8; nf2++) accO[mf][nf2][r] *= alpha;
      }

    // O += P V
#pragma unroll
    for (int ks2 = 0; ks2 < 2; ks2++) {
      bf16x8 pa[2];
#pragma unroll
      for (int mf = 0; mf < 2; mf++) {
        const int rowp = mf * 16 + l16;
        const int ch = (ks2 * 4 + lhi) ^ (rowp & 7);
        pa[mf] =
            *(const bf16x8*)((const char*)Pl + wid * 4096 + rowp * 128 + ch * 16);
      }
#pragma unroll
      for (int nf2 = 0; nf2 < 8; nf2++) {
        const int rowv = nf2 * 16 + l16;
        const int ch = (ks2 * 4 + lhi) ^ (rowv & 7);
        bf16x8 vv = *(const bf16x8*)((const char*)Vt + rowv * 128 + ch * 16);
#pragma unroll
        for (int mf = 0; mf < 2; mf++)
          accO[mf][nf2] = __builtin_amdgcn_mfma_f32_16x16x32_bf16(
              pa[mf], vv, accO[mf][nf2], 0, 0, 0);
      }
    }
    __syncthreads();
  }

#pragma unroll
  for (int mf = 0; mf < 2; mf++)
#pragma unroll
    for (int nf2 = 0; nf2 < 8; nf2++)
#pragma unroll
      for (int r = 0; r < 4; r++) {
        const int qg = q0 + mf * 16 + lhi * 4 + r;
        const int d = nf2 * 16 + l16;
        const float v = accO[mf][nf2][r] / lrow[mf][r];
        AO[((long)(b * SS + qg)) * HID + h * HD + d] = f2bf(v);
      }
}

extern "C" void kernel_launch(void* const* d_in, const int* in_sizes, int n_in,
                              void* d_out, int out_size, void* d_ws,
                              size_t ws_size, hipStream_t stream) {
  (void)in_sizes; (void)n_in; (void)out_size;
  const float* hidden = (const float*)d_in[0];
  const float* amask = (const float*)d_in[1];
  const float* w_qkv = (const float*)d_in[2];
  const float* b_qkv = (const float*)d_in[3];
  const float* w_o = (const float*)d_in[4];
  const float* b_o = (const float*)d_in[5];
  const float* ln1s = (const float*)d_in[6];
  const float* ln1b = (const float*)d_in[7];
  const float* ln2s = (const float*)d_in[8];
  const float* ln2b = (const float*)d_in[9];
  const float* w_in = (const float*)d_in[10];
  const float* b_in = (const float*)d_in[11];
  const float* w_out = (const float*)d_in[12];
  const float* b_out = (const float*)d_in[13];

  char* ws = (char*)d_ws;
  // liveness-aliased workspace (194 MB total; 219 MB known available)
  unsigned short* X1h = (unsigned short*)(ws + 0);           // 16MB, later AO
  unsigned short* X1l = (unsigned short*)(ws + 16777216);    // 16MB, later Vbf
  unsigned short* X2  = (unsigned short*)(ws + 33554432);    // 16MB
  unsigned short* W1h = (unsigned short*)(ws + 50331648);    // 16MB, later Win/Wout
  unsigned short* W1l = (unsigned short*)(ws + 67108864);    // 16MB, later Win/Wout
  unsigned short* WE  = (unsigned short*)(ws + 83886080);    // 8MB: Wv then Wo
  unsigned short* QHb = (unsigned short*)(ws + 92274688);    // 16MB, later H1
  unsigned short* QLb = (unsigned short*)(ws + 109051904);   // 16MB, later H1
  unsigned short* KHb = (unsigned short*)(ws + 125829120);   // 16MB, later H1
  unsigned short* KLb = (unsigned short*)(ws + 142606336);   // 16MB, later H1
  unsigned short* VTb = (unsigned short*)(ws + 159383552);   // 16MB
  unsigned short* ATT = (unsigned short*)(ws + 176160768);   // 16MB
  float2* ROPE = (float2*)(ws + 192937984);                  // 1MB
  if (ws_size < 193986560) return;

  unsigned short* Vbf = X1l;   // x1-lo dead after gemmqk
  unsigned short* AO = X1h;    // x1-hi dead after v-gemm
  unsigned short* WD = W1h;    // 32MB region reused for Win^T / Wout^T
  unsigned short* H1 = QHb;    // 64MB region reused after flash

  ln2k<<<MT, 256, 0, stream>>>(hidden, ln1s, ln1b, ln2s, ln2b, X1h, X1l, X2);
  rope_tab<<<SS, 64, 0, stream>>>(ROPE);
  // q,k: split-precision GEMM + fused rope
  wtrans_hl<<<dim3(128, 64), dim3(32, 8), 0, stream>>>(w_qkv, W1h, W1l,
                                                       HID, 3 * HID);
  gemmqk<<<dim3(32, 32), 256, 0, stream>>>(X1h, X1l, W1h, W1l, b_qkv, ROPE,
                                           QHb, QLb, KHb, KLb);
  // v: plain bf16 GEMM
  wtrans<<<dim3(64, 64), dim3(32, 8), 0, stream>>>(w_qkv, WE, HID, HID,
                                                   3 * HID, 2 * HID);
  gemm128<0><<<dim3(16, 32), 256, 0, stream>>>(X1h, WE, b_qkv + 2 * HID, Vbf,
                                               MT, HID, HID, nullptr, nullptr);
  vtrans<<<dim3(4, 64, 32), dim3(32, 8), 0, stream>>>(Vbf, VTb);
  flash<<<dim3(16, 32), 256, 0, stream>>>(QHb, QLb, KHb, KLb, VTb, amask, AO);
  // attention projection
  wtrans<<<dim3(64, 64), dim3(32, 8), 0, stream>>>(w_o, WE, HID, HID, HID, 0);
  gemm128<0><<<dim3(16, 32), 256, 0, stream>>>(AO, WE, b_o, ATT, MT, HID, HID,
                                               nullptr, nullptr);
  // mlp
  wtrans<<<dim3(256, 64), dim3(32, 8), 0, stream>>>(w_in, WD, HID, INTER,
                                                    INTER, 0);
  gemm128<1><<<dim3(64, 32), 256, 0, stream>>>(X2, WD, b_in, H1, MT, INTER,
                                               HID, nullptr, nullptr);
  wtrans<<<dim3(64, 256), dim3(32, 8), 0, stream>>>(w_out, WD, INTER, HID,
                                                    HID, 0);
  gemm128<2><<<dim3(16, 32), 256, 0, stream>>>(H1, WD, b_out, d_out, MT, HID,
                                               INTER, hidden, ATT);
}

// Round 4
// 1085.773 us; speedup vs baseline: 1.0232x; 1.0232x over previous
//
#include <hip/hip_runtime.h>
#include <math.h>

#define HID 2048
#define NH 16
#define HD 128
#define INTER 8192
#define BB 2
#define SS 2048
#define MT (BB*SS)

typedef __bf16 bf16x8 __attribute__((ext_vector_type(8)));
typedef float f32x4 __attribute__((ext_vector_type(4)));
typedef unsigned short u16x8 __attribute__((ext_vector_type(8)));

__device__ __forceinline__ float bf2f(unsigned short u) {
  unsigned v = ((unsigned)u) << 16;
  return __builtin_bit_cast(float, v);
}
__device__ __forceinline__ unsigned short f2bf(float x) {
  unsigned u = __builtin_bit_cast(unsigned, x);
  u += 0x7fffu + ((u >> 16) & 1u);
  return (unsigned short)(u >> 16);
}
__device__ __forceinline__ void gll16(const void* g, const void* lds) {
  __builtin_amdgcn_global_load_lds(
      (const __attribute__((address_space(1))) void*)g,
      (__attribute__((address_space(3))) void*)lds, 16, 0, 0);
}

// ---------------- fused LayerNorm: x1 as hi/lo split, x2 plain bf16 --------
__global__ __launch_bounds__(256) void ln2k(
    const float* __restrict__ X, const float* __restrict__ s1,
    const float* __restrict__ b1, const float* __restrict__ s2,
    const float* __restrict__ b2, unsigned short* __restrict__ X1h,
    unsigned short* __restrict__ X1l, unsigned short* __restrict__ X2) {
  const int row = blockIdx.x;
  const int tid = threadIdx.x;
  const float* x = X + (long)row * HID;
  float4 v0 = ((const float4*)x)[tid * 2];
  float4 v1 = ((const float4*)x)[tid * 2 + 1];
  float s = v0.x + v0.y + v0.z + v0.w + v1.x + v1.y + v1.z + v1.w;
  float q = v0.x * v0.x + v0.y * v0.y + v0.z * v0.z + v0.w * v0.w +
            v1.x * v1.x + v1.y * v1.y + v1.z * v1.z + v1.w * v1.w;
#pragma unroll
  for (int off = 1; off < 64; off <<= 1) {
    s += __shfl_xor(s, off);
    q += __shfl_xor(q, off);
  }
  __shared__ float rs[4], rq[4];
  const int wid = tid >> 6, lane = tid & 63;
  if (lane == 0) { rs[wid] = s; rq[wid] = q; }
  __syncthreads();
  s = rs[0] + rs[1] + rs[2] + rs[3];
  q = rq[0] + rq[1] + rq[2] + rq[3];
  const float mu = s * (1.f / HID);
  const float var = q * (1.f / HID) - mu * mu;
  const float rstd = rsqrtf(var + 1e-5f);
  float xv[8] = {v0.x, v0.y, v0.z, v0.w, v1.x, v1.y, v1.z, v1.w};
  u16x8 o1h, o1l, o2;
#pragma unroll
  for (int e = 0; e < 8; e++) {
    const int j = tid * 8 + e;
    const float xn = (xv[e] - mu) * rstd;
    const float x1v = xn * s1[j] + b1[j];
    const unsigned short h = f2bf(x1v);
    o1h[e] = h;
    o1l[e] = f2bf(x1v - bf2f(h));
    o2[e] = f2bf(xn * s2[j] + b2[j]);
  }
  *(u16x8*)(X1h + (long)row * HID + tid * 8) = o1h;
  *(u16x8*)(X1l + (long)row * HID + tid * 8) = o1l;
  *(u16x8*)(X2 + (long)row * HID + tid * 8) = o2;
}

// ------- weight transpose + f32->bf16: W[k][ldn] cols [coff,coff+N) -------
__global__ __launch_bounds__(256) void wtrans(const float* __restrict__ W,
                                              unsigned short* __restrict__ WT,
                                              int K, int N, int ldn, int coff) {
  (void)N;
  __shared__ float t[32][33];
  const int n0 = blockIdx.x * 32, k0 = blockIdx.y * 32;
  const int tx = threadIdx.x, ty = threadIdx.y;
#pragma unroll
  for (int r = 0; r < 4; r++)
    t[ty + r * 8][tx] = W[(long)(k0 + ty + r * 8) * ldn + coff + n0 + tx];
  __syncthreads();
#pragma unroll
  for (int r = 0; r < 4; r++)
    WT[(long)(n0 + ty + r * 8) * K + k0 + tx] = f2bf(t[tx][ty + r * 8]);
}

// ------- same but hi/lo split output (for the q,k half of w_qkv) ----------
__global__ __launch_bounds__(256) void wtrans_hl(
    const float* __restrict__ W, unsigned short* __restrict__ WTh,
    unsigned short* __restrict__ WTl, int K, int ldn) {
  __shared__ float t[32][33];
  const int n0 = blockIdx.x * 32, k0 = blockIdx.y * 32;
  const int tx = threadIdx.x, ty = threadIdx.y;
#pragma unroll
  for (int r = 0; r < 4; r++)
    t[ty + r * 8][tx] = W[(long)(k0 + ty + r * 8) * ldn + n0 + tx];
  __syncthreads();
#pragma unroll
  for (int r = 0; r < 4; r++) {
    const float v = t[tx][ty + r * 8];
    const unsigned short h = f2bf(v);
    const long o = (long)(n0 + ty + r * 8) * K + k0 + tx;
    WTh[o] = h;
    WTl[o] = f2bf(v - bf2f(h));
  }
}

// ---------------- rope cos/sin table (f64 angle for accuracy) --------------
__global__ void rope_tab(float2* __restrict__ rope) {
  const int s = blockIdx.x, i = threadIdx.x;  // 2048 x 64
  const double ang = (double)s * pow(10000.0, -(double)i / 64.0);
  rope[s * 64 + i] = make_float2((float)cos(ang), (float)sin(ang));
}

// ---- split-precision GEMM for q,k (3-MFMA bf16 split) + fused RoPE -------
__global__ __launch_bounds__(256) void gemmqk(
    const unsigned short* __restrict__ Ah_, const unsigned short* __restrict__ Al_,
    const unsigned short* __restrict__ Bh_, const unsigned short* __restrict__ Bl_,
    const float* __restrict__ bias, const float2* __restrict__ rope,
    unsigned short* __restrict__ QH, unsigned short* __restrict__ QL,
    unsigned short* __restrict__ KH, unsigned short* __restrict__ KL) {
  __shared__ unsigned short Ash[128 * 64], Asl[128 * 64];
  __shared__ unsigned short Bsh[128 * 64], Bsl[128 * 64];
  const int K = HID;
  const int tid = threadIdx.x;
  const int wid = tid >> 6, lane = tid & 63;
  const int l16 = lane & 15, lhi = lane >> 4;
  const int bn = blockIdx.x, bm = blockIdx.y;
  const int wr = wid >> 1, wc = wid & 1;
  const long rA0 = (long)bm * 128;
  const long rB0 = (long)bn * 128;

  f32x4 acc[4][4] = {};

  for (int kt = 0; kt < K; kt += 64) {
#pragma unroll
    for (int i = 0; i < 4; i++) {
      const int lin = i * 4096 + wid * 1024 + (lane << 4);
      const int row = lin >> 7;
      const int cs = ((lin >> 4) & 7) ^ (row & 7);
      const int dst = i * 4096 + wid * 1024;
      const long ga = (rA0 + row) * (long)K + kt + cs * 8;
      const long gb = (rB0 + row) * (long)K + kt + cs * 8;
      gll16(Ah_ + ga, (const char*)Ash + dst);
      gll16(Al_ + ga, (const char*)Asl + dst);
      gll16(Bh_ + gb, (const char*)Bsh + dst);
      gll16(Bl_ + gb, (const char*)Bsl + dst);
    }
    __syncthreads();
#pragma unroll
    for (int ks = 0; ks < 2; ks++) {
      bf16x8 avh[4], avl[4], bvh[4], bvl[4];
#pragma unroll
      for (int m = 0; m < 4; m++) {
        const int row = wr * 64 + m * 16 + l16;
        const int ch = (ks * 4 + lhi) ^ (row & 7);
        avh[m] = *(const bf16x8*)((const char*)Ash + row * 128 + ch * 16);
        avl[m] = *(const bf16x8*)((const char*)Asl + row * 128 + ch * 16);
      }
#pragma unroll
      for (int n = 0; n < 4; n++) {
        const int row = wc * 64 + n * 16 + l16;
        const int ch = (ks * 4 + lhi) ^ (row & 7);
        bvh[n] = *(const bf16x8*)((const char*)Bsh + row * 128 + ch * 16);
        bvl[n] = *(const bf16x8*)((const char*)Bsl + row * 128 + ch * 16);
      }
#pragma unroll
      for (int m = 0; m < 4; m++)
#pragma unroll
        for (int n = 0; n < 4; n++) {
          acc[m][n] = __builtin_amdgcn_mfma_f32_16x16x32_bf16(avh[m], bvl[n],
                                                              acc[m][n], 0, 0, 0);
          acc[m][n] = __builtin_amdgcn_mfma_f32_16x16x32_bf16(avl[m], bvh[n],
                                                              acc[m][n], 0, 0, 0);
          acc[m][n] = __builtin_amdgcn_mfma_f32_16x16x32_bf16(avh[m], bvh[n],
                                                              acc[m][n], 0, 0, 0);
        }
    }
    __syncthreads();
  }

  const int b_ = (int)(rA0 >> 11);
#pragma unroll
  for (int m = 0; m < 4; m++) {
#pragma unroll
    for (int n = 0; n < 4; n++) {
      const int col = (int)rB0 + wc * 64 + n * 16 + l16;
      const float bsv = bias[col];
      const int i = (col & 127) >> 1;
      const int hh = (col >> 7) & 15;
      const int d = col & 127;
#pragma unroll
      for (int r = 0; r < 4; r++) {
        const int row = (int)rA0 + wr * 64 + m * 16 + lhi * 4 + r;
        const int srow = row & 2047;
        const float v = acc[m][n][r] + bsv;
        const float p = __shfl_xor(v, 1);
        const float2 cs = rope[srow * 64 + i];
        const float o = ((lane & 1) == 0) ? (v * cs.x - p * cs.y)
                                          : (p * cs.y + v * cs.x);
        const unsigned short hi = f2bf(o);
        const unsigned short lo = f2bf(o - bf2f(hi));
        const long dst = ((long)(b_ * NH + hh) * SS + srow) * HD + d;
        if (col < 2048) { QH[dst] = hi; QL[dst] = lo; }
        else            { KH[dst] = hi; KL[dst] = lo; }
      }
    }
  }
}

// ---------------- V transpose: Vbf [m][2048] -> VT [bh][128][s] ------------
__global__ __launch_bounds__(256) void vtrans(
    const unsigned short* __restrict__ Vb, unsigned short* __restrict__ VTb) {
  __shared__ unsigned short t[32][33];
  const int bh = blockIdx.z, b = bh >> 4, h = bh & 15;
  const int d0 = blockIdx.x * 32, s0 = blockIdx.y * 32;
  const int tx = threadIdx.x, ty = threadIdx.y;
#pragma unroll
  for (int r = 0; r < 4; r++) {
    const int s = s0 + ty + r * 8;
    t[ty + r * 8][tx] = Vb[((long)(b * SS + s)) * HID + h * HD + d0 + tx];
  }
  __syncthreads();
#pragma unroll
  for (int r = 0; r < 4; r++) {
    const int d = d0 + ty + r * 8;
    VTb[((long)bh * HD + d) * SS + s0 + tx] = t[tx][ty + r * 8];
  }
}

// ---------------- 128x128-tile plain bf16 GEMM ----------------
template <int MODE>
__global__ __launch_bounds__(256) void gemm128(
    const unsigned short* __restrict__ A, const unsigned short* __restrict__ Bt,
    const float* __restrict__ bias, void* __restrict__ Cout, int M, int N,
    int K, const float* __restrict__ residF,
    const unsigned short* __restrict__ residB) {
  (void)M;
  __shared__ unsigned short As[128 * 64];
  __shared__ unsigned short Bs[128 * 64];
  const int tid = threadIdx.x;
  const int wid = tid >> 6, lane = tid & 63;
  const int l16 = lane & 15, lhi = lane >> 4;
  const int bn = blockIdx.x, bm = blockIdx.y;
  const int wr = wid >> 1, wc = wid & 1;
  const long rA0 = (long)bm * 128;
  const long rB0 = (long)bn * 128;

  f32x4 acc[4][4] = {};

  for (int kt = 0; kt < K; kt += 64) {
#pragma unroll
    for (int i = 0; i < 4; i++) {
      const int lin = i * 4096 + wid * 1024 + (lane << 4);
      const int row = lin >> 7;
      const int cs = ((lin >> 4) & 7) ^ (row & 7);
      gll16(A + (rA0 + row) * (long)K + kt + cs * 8,
            (const char*)As + (i * 4096 + wid * 1024));
      gll16(Bt + (rB0 + row) * (long)K + kt + cs * 8,
            (const char*)Bs + (i * 4096 + wid * 1024));
    }
    __syncthreads();
#pragma unroll
    for (int ks = 0; ks < 2; ks++) {
      bf16x8 av[4], bv[4];
#pragma unroll
      for (int m = 0; m < 4; m++) {
        const int row = wr * 64 + m * 16 + l16;
        const int ch = (ks * 4 + lhi) ^ (row & 7);
        av[m] = *(const bf16x8*)((const char*)As + row * 128 + ch * 16);
      }
#pragma unroll
      for (int n = 0; n < 4; n++) {
        const int row = wc * 64 + n * 16 + l16;
        const int ch = (ks * 4 + lhi) ^ (row & 7);
        bv[n] = *(const bf16x8*)((const char*)Bs + row * 128 + ch * 16);
      }
#pragma unroll
      for (int m = 0; m < 4; m++)
#pragma unroll
        for (int n = 0; n < 4; n++)
          acc[m][n] = __builtin_amdgcn_mfma_f32_16x16x32_bf16(av[m], bv[n],
                                                              acc[m][n], 0, 0, 0);
    }
    __syncthreads();
  }

#pragma unroll
  for (int m = 0; m < 4; m++) {
#pragma unroll
    for (int n = 0; n < 4; n++) {
      const long col = rB0 + wc * 64 + n * 16 + l16;
      const float bsv = bias[col];
#pragma unroll
      for (int r = 0; r < 4; r++) {
        const long row = rA0 + wr * 64 + m * 16 + lhi * 4 + r;
        float v = acc[m][n][r] + bsv;
        if (MODE == 1) v = 0.5f * v * (1.f + erff(v * 0.7071067811865475f));
        if (MODE == 2) {
          v += residF[row * N + col] + bf2f(residB[row * N + col]);
          ((float*)Cout)[row * N + col] = v;
        } else {
          ((unsigned short*)Cout)[row * N + col] = f2bf(v);
        }
      }
    }
  }
}

// ------- flash attention v2: dbuf pipeline + counted vmcnt + exp2 ----------
// QH/QL/KH/KL: [bh][s][128]; VT: [bh][128][s]; AO: [b][s][h*128+d] bf16
__global__ __launch_bounds__(256) void flash(
    const unsigned short* __restrict__ QH, const unsigned short* __restrict__ QL,
    const unsigned short* __restrict__ KH, const unsigned short* __restrict__ KL,
    const unsigned short* __restrict__ VT, const float* __restrict__ amask,
    unsigned short* __restrict__ AO) {
  __shared__ unsigned short Kth[2][64 * 128];  // 32KB  [key][d] hi, dbuf
  __shared__ unsigned short Ktl[2][64 * 128];  // 32KB  [key][d] lo, dbuf
  __shared__ unsigned short Vt[2][128 * 64];   // 32KB  [d][key], dbuf
  __shared__ unsigned short Pl[4 * 2048];      // 16KB  per-wave 32x64 P
  __shared__ float maskL[SS];                  // 8KB   amask*log2e
  const int qt = gridDim.x - 1 - blockIdx.x;   // big tiles scheduled first
  const int bh = blockIdx.y;
  const int b = bh >> 4, h = bh & 15;
  const int tid = threadIdx.x, wid = tid >> 6, lane = tid & 63;
  const int l16 = lane & 15, lhi = lane >> 4;
  const unsigned short* Qhb = QH + (long)bh * SS * HD;
  const unsigned short* Qlb = QL + (long)bh * SS * HD;
  const unsigned short* Khb = KH + (long)bh * SS * HD;
  const unsigned short* Klb = KL + (long)bh * SS * HD;
  const unsigned short* Vb = VT + (long)bh * HD * SS;
  const int q0 = qt * 128 + wid * 32;
  const float LOG2E = 1.4426950408889634f;
  const float SCL2 = 16.322232154552f;  // sqrt(128)*log2e

  // amask row -> LDS (prescaled); keeps the K-loop free of global loads
  {
    const float4* mg = (const float4*)(amask + (long)b * SS);
    float4 m0 = mg[tid * 2], m1 = mg[tid * 2 + 1];
    m0.x *= LOG2E; m0.y *= LOG2E; m0.z *= LOG2E; m0.w *= LOG2E;
    m1.x *= LOG2E; m1.y *= LOG2E; m1.z *= LOG2E; m1.w *= LOG2E;
    ((float4*)maskL)[tid * 2] = m0;
    ((float4*)maskL)[tid * 2 + 1] = m1;
  }

  bf16x8 qfh[2][4], qfl[2][4];
#pragma unroll
  for (int mf = 0; mf < 2; mf++)
#pragma unroll
    for (int ks = 0; ks < 4; ks++) {
      const long o = (long)(q0 + mf * 16 + l16) * HD + ks * 32 + lhi * 8;
      qfh[mf][ks] = *(const bf16x8*)(Qhb + o);
      qfl[mf][ks] = *(const bf16x8*)(Qlb + o);
    }

  // stage tile kt2 into buffer bu (12 loads/thread = 48KB/block)
  auto stage = [&](int kt2, int bu) {
#pragma unroll
    for (int i = 0; i < 4; i++) {
      const int lin = i * 4096 + wid * 1024 + (lane << 4);
      const int dst = i * 4096 + wid * 1024;
      {
        const int row = lin >> 8;
        const int cs = ((lin >> 4) & 15) ^ (row & 7);
        const long g = (long)(kt2 * 64 + row) * HD + cs * 8;
        gll16(Khb + g, (const char*)Kth[bu] + dst);
        gll16(Klb + g, (const char*)Ktl[bu] + dst);
      }
      {
        const int row = lin >> 7;
        const int cs = ((lin >> 4) & 7) ^ (row & 7);
        gll16(Vb + (long)row * SS + kt2 * 64 + cs * 8,
              (const char*)Vt[bu] + dst);
      }
    }
  };

  f32x4 accO[2][8] = {};
  float mrow[2][4], lrow[2][4];
#pragma unroll
  for (int mf = 0; mf < 2; mf++)
#pragma unroll
    for (int r = 0; r < 4; r++) { mrow[mf][r] = -3e38f; lrow[mf][r] = 0.f; }

  const int nkt = 2 * qt + 2;
  stage(0, 0);
  int buf = 0;
  for (int kt = 0; kt < nkt; kt++) {
    if (kt + 1 < nkt) {
      stage(kt + 1, buf ^ 1);  // prefetch next tile; stays in flight
      asm volatile("s_waitcnt vmcnt(12)" ::: "memory");  // wait current only
    } else {
      asm volatile("s_waitcnt vmcnt(0)" ::: "memory");
    }
    __syncthreads();

    // S = (Qh+Ql)(Kh+Kl)^T  (3-term split)
    f32x4 accS[2][4] = {};
    __builtin_amdgcn_s_setprio(1);
#pragma unroll
    for (int ks = 0; ks < 4; ks++) {
      bf16x8 bkh[4], bkl[4];
#pragma unroll
      for (int nf = 0; nf < 4; nf++) {
        const int row = nf * 16 + l16;
        const int ch = (ks * 4 + lhi) ^ (row & 7);
        bkh[nf] = *(const bf16x8*)((const char*)Kth[buf] + row * 256 + ch * 16);
        bkl[nf] = *(const bf16x8*)((const char*)Ktl[buf] + row * 256 + ch * 16);
      }
#pragma unroll
      for (int mf = 0; mf < 2; mf++)
#pragma unroll
        for (int nf = 0; nf < 4; nf++) {
          accS[mf][nf] = __builtin_amdgcn_mfma_f32_16x16x32_bf16(
              qfh[mf][ks], bkl[nf], accS[mf][nf], 0, 0, 0);
          accS[mf][nf] = __builtin_amdgcn_mfma_f32_16x16x32_bf16(
              qfl[mf][ks], bkh[nf], accS[mf][nf], 0, 0, 0);
          accS[mf][nf] = __builtin_amdgcn_mfma_f32_16x16x32_bf16(
              qfh[mf][ks], bkh[nf], accS[mf][nf], 0, 0, 0);
        }
    }
    __builtin_amdgcn_s_setprio(0);

    // scale to log2 domain + mask + causal
    float mk[4];
#pragma unroll
    for (int nf = 0; nf < 4; nf++) mk[nf] = maskL[kt * 64 + nf * 16 + l16];
#pragma unroll
    for (int mf = 0; mf < 2; mf++)
#pragma unroll
      for (int nf = 0; nf < 4; nf++)
#pragma unroll
        for (int r = 0; r < 4; r++) {
          const int key = kt * 64 + nf * 16 + l16;
          const int qg = q0 + mf * 16 + lhi * 4 + r;
          const float sv = accS[mf][nf][r] * SCL2 + mk[nf];
          accS[mf][nf][r] = (key > qg) ? -1e30f : sv;
        }

    // row maxes (4 shfl over the 16-lane group)
    float mx[2][4];
#pragma unroll
    for (int mf = 0; mf < 2; mf++)
#pragma unroll
      for (int r = 0; r < 4; r++) {
        float m0 = fmaxf(fmaxf(accS[mf][0][r], accS[mf][1][r]),
                         fmaxf(accS[mf][2][r], accS[mf][3][r]));
        m0 = fmaxf(m0, __shfl_xor(m0, 1));
        m0 = fmaxf(m0, __shfl_xor(m0, 2));
        m0 = fmaxf(m0, __shfl_xor(m0, 4));
        m0 = fmaxf(m0, __shfl_xor(m0, 8));
        mx[mf][r] = m0;
      }
    // defer-rescale: skip m-update + O-rescale when max grew by <= 8 (log2)
    bool defer = true;
#pragma unroll
    for (int mf = 0; mf < 2; mf++)
#pragma unroll
      for (int r = 0; r < 4; r++)
        defer = defer && (mx[mf][r] <= mrow[mf][r] + 8.f);
    if (!__all(defer)) {
#pragma unroll
      for (int mf = 0; mf < 2; mf++)
#pragma unroll
        for (int r = 0; r < 4; r++) {
          const float mnew = fmaxf(mrow[mf][r], mx[mf][r]);
          const float alpha = exp2f(mrow[mf][r] - mnew);
          mrow[mf][r] = mnew;
          lrow[mf][r] *= alpha;
#pragma unroll
          for (int nf2 = 0; nf2 < 8; nf2++) accO[mf][nf2][r] *= alpha;
        }
    }
    // P = exp2(S - m), write bf16 to per-wave LDS; accumulate row sums
#pragma unroll
    for (int mf = 0; mf < 2; mf++)
#pragma unroll
      for (int r = 0; r < 4; r++) {
        const int rowl = mf * 16 + lhi * 4 + r;
        const int qg = q0 + rowl;
        float rsum = 0.f;
#pragma unroll
        for (int nf = 0; nf < 4; nf++) {
          const int key = kt * 64 + nf * 16 + l16;
          const float p =
              (key > qg) ? 0.f : exp2f(accS[mf][nf][r] - mrow[mf][r]);
          rsum += p;
          const int colv = nf * 16 + l16;
          const int slot = (colv >> 3) ^ (rowl & 7);
          Pl[wid * 2048 + rowl * 64 + slot * 8 + (colv & 7)] = f2bf(p);
        }
        rsum += __shfl_xor(rsum, 1);
        rsum += __shfl_xor(rsum, 2);
        rsum += __shfl_xor(rsum, 4);
        rsum += __shfl_xor(rsum, 8);
        lrow[mf][r] += rsum;
      }

    // O += P V
    __builtin_amdgcn_s_setprio(1);
#pragma unroll
    for (int ks2 = 0; ks2 < 2; ks2++) {
      bf16x8 pa[2];
#pragma unroll
      for (int mf = 0; mf < 2; mf++) {
        const int rowp = mf * 16 + l16;
        const int ch = (ks2 * 4 + lhi) ^ (rowp & 7);
        pa[mf] =
            *(const bf16x8*)((const char*)Pl + wid * 4096 + rowp * 128 + ch * 16);
      }
#pragma unroll
      for (int nf2 = 0; nf2 < 8; nf2++) {
        const int rowv = nf2 * 16 + l16;
        const int ch = (ks2 * 4 + lhi) ^ (rowv & 7);
        bf16x8 vv =
            *(const bf16x8*)((const char*)Vt[buf] + rowv * 128 + ch * 16);
#pragma unroll
        for (int mf = 0; mf < 2; mf++)
          accO[mf][nf2] = __builtin_amdgcn_mfma_f32_16x16x32_bf16(
              pa[mf], vv, accO[mf][nf2], 0, 0, 0);
      }
    }
    __builtin_amdgcn_s_setprio(0);
    __syncthreads();  // all waves done with buf before it is restaged
    buf ^= 1;
  }

#pragma unroll
  for (int mf = 0; mf < 2; mf++)
#pragma unroll
    for (int nf2 = 0; nf2 < 8; nf2++)
#pragma unroll
      for (int r = 0; r < 4; r++) {
        const int qg = q0 + mf * 16 + lhi * 4 + r;
        const int d = nf2 * 16 + l16;
        const float v = accO[mf][nf2][r] / lrow[mf][r];
        AO[((long)(b * SS + qg)) * HID + h * HD + d] = f2bf(v);
      }
}

extern "C" void kernel_launch(void* const* d_in, const int* in_sizes, int n_in,
                              void* d_out, int out_size, void* d_ws,
                              size_t ws_size, hipStream_t stream) {
  (void)in_sizes; (void)n_in; (void)out_size;
  const float* hidden = (const float*)d_in[0];
  const float* amask = (const float*)d_in[1];
  const float* w_qkv = (const float*)d_in[2];
  const float* b_qkv = (const float*)d_in[3];
  const float* w_o = (const float*)d_in[4];
  const float* b_o = (const float*)d_in[5];
  const float* ln1s = (const float*)d_in[6];
  const float* ln1b = (const float*)d_in[7];
  const float* ln2s = (const float*)d_in[8];
  const float* ln2b = (const float*)d_in[9];
  const float* w_in = (const float*)d_in[10];
  const float* b_in = (const float*)d_in[11];
  const float* w_out = (const float*)d_in[12];
  const float* b_out = (const float*)d_in[13];

  char* ws = (char*)d_ws;
  // liveness-aliased workspace (194 MB total; 219 MB known available)
  unsigned short* X1h = (unsigned short*)(ws + 0);           // 16MB, later AO
  unsigned short* X1l = (unsigned short*)(ws + 16777216);    // 16MB, later Vbf
  unsigned short* X2  = (unsigned short*)(ws + 33554432);    // 16MB
  unsigned short* W1h = (unsigned short*)(ws + 50331648);    // 16MB, later Win/Wout
  unsigned short* W1l = (unsigned short*)(ws + 67108864);    // 16MB, later Win/Wout
  unsigned short* WE  = (unsigned short*)(ws + 83886080);    // 8MB: Wv then Wo
  unsigned short* QHb = (unsigned short*)(ws + 92274688);    // 16MB, later H1
  unsigned short* QLb = (unsigned short*)(ws + 109051904);   // 16MB, later H1
  unsigned short* KHb = (unsigned short*)(ws + 125829120);   // 16MB, later H1
  unsigned short* KLb = (unsigned short*)(ws + 142606336);   // 16MB, later H1
  unsigned short* VTb = (unsigned short*)(ws + 159383552);   // 16MB
  unsigned short* ATT = (unsigned short*)(ws + 176160768);   // 16MB
  float2* ROPE = (float2*)(ws + 192937984);                  // 1MB
  if (ws_size < 193986560) return;

  unsigned short* Vbf = X1l;   // x1-lo dead after gemmqk
  unsigned short* AO = X1h;    // x1-hi dead after v-gemm
  unsigned short* WD = W1h;    // 32MB region reused for Win^T / Wout^T
  unsigned short* H1 = QHb;    // 64MB region reused after flash

  ln2k<<<MT, 256, 0, stream>>>(hidden, ln1s, ln1b, ln2s, ln2b, X1h, X1l, X2);
  rope_tab<<<SS, 64, 0, stream>>>(ROPE);
  // q,k: split-precision GEMM + fused rope
  wtrans_hl<<<dim3(128, 64), dim3(32, 8), 0, stream>>>(w_qkv, W1h, W1l,
                                                       HID, 3 * HID);
  gemmqk<<<dim3(32, 32), 256, 0, stream>>>(X1h, X1l, W1h, W1l, b_qkv, ROPE,
                                           QHb, QLb, KHb, KLb);
  // v: plain bf16 GEMM
  wtrans<<<dim3(64, 64), dim3(32, 8), 0, stream>>>(w_qkv, WE, HID, HID,
                                                   3 * HID, 2 * HID);
  gemm128<0><<<dim3(16, 32), 256, 0, stream>>>(X1h, WE, b_qkv + 2 * HID, Vbf,
                                               MT, HID, HID, nullptr, nullptr);
  vtrans<<<dim3(4, 64, 32), dim3(32, 8), 0, stream>>>(Vbf, VTb);
  flash<<<dim3(16, 32), 256, 0, stream>>>(QHb, QLb, KHb, KLb, VTb, amask, AO);
  // attention projection
  wtrans<<<dim3(64, 64), dim3(32, 8), 0, stream>>>(w_o, WE, HID, HID, HID, 0);
  gemm128<0><<<dim3(16, 32), 256, 0, stream>>>(AO, WE, b_o, ATT, MT, HID, HID,
                                               nullptr, nullptr);
  // mlp
  wtrans<<<dim3(256, 64), dim3(32, 8), 0, stream>>>(w_in, WD, HID, INTER,
                                                    INTER, 0);
  gemm128<1><<<dim3(64, 32), 256, 0, stream>>>(X2, WD, b_in, H1, MT, INTER,
                                               HID, nullptr, nullptr);
  wtrans<<<dim3(64, 256), dim3(32, 8), 0, stream>>>(w_out, WD, INTER, HID,
                                                    HID, 0);
  gemm128<2><<<dim3(16, 32), 256, 0, stream>>>(H1, WD, b_out, d_out, MT, HID,
                                               INTER, hidden, ATT);
}

// Round 5
// 935.711 us; speedup vs baseline: 1.1873x; 1.1604x over previous
//
#include <hip/hip_runtime.h>
#include <math.h>

#define HID 2048
#define NH 16
#define HD 128
#define INTER 8192
#define BB 2
#define SS 2048
#define MT (BB*SS)

typedef __bf16 bf16x8 __attribute__((ext_vector_type(8)));
typedef float f32x4 __attribute__((ext_vector_type(4)));
typedef unsigned short u16x8 __attribute__((ext_vector_type(8)));

__device__ __forceinline__ float bf2f(unsigned short u) {
  unsigned v = ((unsigned)u) << 16;
  return __builtin_bit_cast(float, v);
}
__device__ __forceinline__ unsigned short f2bf(float x) {
  unsigned u = __builtin_bit_cast(unsigned, x);
  u += 0x7fffu + ((u >> 16) & 1u);
  return (unsigned short)(u >> 16);
}
__device__ __forceinline__ void gll16(const void* g, const void* lds) {
  __builtin_amdgcn_global_load_lds(
      (const __attribute__((address_space(1))) void*)g,
      (__attribute__((address_space(3))) void*)lds, 16, 0, 0);
}

// ---------------- fused LayerNorm: x1 as hi/lo split, x2 plain bf16 --------
__global__ __launch_bounds__(256) void ln2k(
    const float* __restrict__ X, const float* __restrict__ s1,
    const float* __restrict__ b1, const float* __restrict__ s2,
    const float* __restrict__ b2, unsigned short* __restrict__ X1h,
    unsigned short* __restrict__ X1l, unsigned short* __restrict__ X2) {
  const int row = blockIdx.x;
  const int tid = threadIdx.x;
  const float* x = X + (long)row * HID;
  float4 v0 = ((const float4*)x)[tid * 2];
  float4 v1 = ((const float4*)x)[tid * 2 + 1];
  float s = v0.x + v0.y + v0.z + v0.w + v1.x + v1.y + v1.z + v1.w;
  float q = v0.x * v0.x + v0.y * v0.y + v0.z * v0.z + v0.w * v0.w +
            v1.x * v1.x + v1.y * v1.y + v1.z * v1.z + v1.w * v1.w;
#pragma unroll
  for (int off = 1; off < 64; off <<= 1) {
    s += __shfl_xor(s, off);
    q += __shfl_xor(q, off);
  }
  __shared__ float rs[4], rq[4];
  const int wid = tid >> 6, lane = tid & 63;
  if (lane == 0) { rs[wid] = s; rq[wid] = q; }
  __syncthreads();
  s = rs[0] + rs[1] + rs[2] + rs[3];
  q = rq[0] + rq[1] + rq[2] + rq[3];
  const float mu = s * (1.f / HID);
  const float var = q * (1.f / HID) - mu * mu;
  const float rstd = rsqrtf(var + 1e-5f);
  float xv[8] = {v0.x, v0.y, v0.z, v0.w, v1.x, v1.y, v1.z, v1.w};
  u16x8 o1h, o1l, o2;
#pragma unroll
  for (int e = 0; e < 8; e++) {
    const int j = tid * 8 + e;
    const float xn = (xv[e] - mu) * rstd;
    const float x1v = xn * s1[j] + b1[j];
    const unsigned short h = f2bf(x1v);
    o1h[e] = h;
    o1l[e] = f2bf(x1v - bf2f(h));
    o2[e] = f2bf(xn * s2[j] + b2[j]);
  }
  *(u16x8*)(X1h + (long)row * HID + tid * 8) = o1h;
  *(u16x8*)(X1l + (long)row * HID + tid * 8) = o1l;
  *(u16x8*)(X2 + (long)row * HID + tid * 8) = o2;
}

// ------- weight transpose + f32->bf16: W[k][ldn] cols [coff,coff+N) -------
__global__ __launch_bounds__(256) void wtrans(const float* __restrict__ W,
                                              unsigned short* __restrict__ WT,
                                              int K, int N, int ldn, int coff) {
  (void)N;
  __shared__ float t[32][33];
  const int n0 = blockIdx.x * 32, k0 = blockIdx.y * 32;
  const int tx = threadIdx.x, ty = threadIdx.y;
#pragma unroll
  for (int r = 0; r < 4; r++)
    t[ty + r * 8][tx] = W[(long)(k0 + ty + r * 8) * ldn + coff + n0 + tx];
  __syncthreads();
#pragma unroll
  for (int r = 0; r < 4; r++)
    WT[(long)(n0 + ty + r * 8) * K + k0 + tx] = f2bf(t[tx][ty + r * 8]);
}

// ------- same but hi/lo split output (for the q,k half of w_qkv) ----------
__global__ __launch_bounds__(256) void wtrans_hl(
    const float* __restrict__ W, unsigned short* __restrict__ WTh,
    unsigned short* __restrict__ WTl, int K, int ldn) {
  __shared__ float t[32][33];
  const int n0 = blockIdx.x * 32, k0 = blockIdx.y * 32;
  const int tx = threadIdx.x, ty = threadIdx.y;
#pragma unroll
  for (int r = 0; r < 4; r++)
    t[ty + r * 8][tx] = W[(long)(k0 + ty + r * 8) * ldn + n0 + tx];
  __syncthreads();
#pragma unroll
  for (int r = 0; r < 4; r++) {
    const float v = t[tx][ty + r * 8];
    const unsigned short h = f2bf(v);
    const long o = (long)(n0 + ty + r * 8) * K + k0 + tx;
    WTh[o] = h;
    WTl[o] = f2bf(v - bf2f(h));
  }
}

// ---------------- rope cos/sin table (f64 angle for accuracy) --------------
__global__ void rope_tab(float2* __restrict__ rope) {
  const int s = blockIdx.x, i = threadIdx.x;  // 2048 x 64
  const double ang = (double)s * pow(10000.0, -(double)i / 64.0);
  rope[s * 64 + i] = make_float2((float)cos(ang), (float)sin(ang));
}

// ---- split-precision GEMM for q,k (3-MFMA bf16 split) + fused RoPE -------
__global__ __launch_bounds__(256) void gemmqk(
    const unsigned short* __restrict__ Ah_, const unsigned short* __restrict__ Al_,
    const unsigned short* __restrict__ Bh_, const unsigned short* __restrict__ Bl_,
    const float* __restrict__ bias, const float2* __restrict__ rope,
    unsigned short* __restrict__ QH, unsigned short* __restrict__ QL,
    unsigned short* __restrict__ KH, unsigned short* __restrict__ KL) {
  __shared__ unsigned short Ash[128 * 64], Asl[128 * 64];
  __shared__ unsigned short Bsh[128 * 64], Bsl[128 * 64];
  const int K = HID;
  const int tid = threadIdx.x;
  const int wid = tid >> 6, lane = tid & 63;
  const int l16 = lane & 15, lhi = lane >> 4;
  const int bn = blockIdx.x, bm = blockIdx.y;
  const int wr = wid >> 1, wc = wid & 1;
  const long rA0 = (long)bm * 128;
  const long rB0 = (long)bn * 128;

  f32x4 acc[4][4] = {};

  for (int kt = 0; kt < K; kt += 64) {
#pragma unroll
    for (int i = 0; i < 4; i++) {
      const int lin = i * 4096 + wid * 1024 + (lane << 4);
      const int row = lin >> 7;
      const int cs = ((lin >> 4) & 7) ^ (row & 7);
      const int dst = i * 4096 + wid * 1024;
      const long ga = (rA0 + row) * (long)K + kt + cs * 8;
      const long gb = (rB0 + row) * (long)K + kt + cs * 8;
      gll16(Ah_ + ga, (const char*)Ash + dst);
      gll16(Al_ + ga, (const char*)Asl + dst);
      gll16(Bh_ + gb, (const char*)Bsh + dst);
      gll16(Bl_ + gb, (const char*)Bsl + dst);
    }
    __syncthreads();
#pragma unroll
    for (int ks = 0; ks < 2; ks++) {
      bf16x8 avh[4], avl[4], bvh[4], bvl[4];
#pragma unroll
      for (int m = 0; m < 4; m++) {
        const int row = wr * 64 + m * 16 + l16;
        const int ch = (ks * 4 + lhi) ^ (row & 7);
        avh[m] = *(const bf16x8*)((const char*)Ash + row * 128 + ch * 16);
        avl[m] = *(const bf16x8*)((const char*)Asl + row * 128 + ch * 16);
      }
#pragma unroll
      for (int n = 0; n < 4; n++) {
        const int row = wc * 64 + n * 16 + l16;
        const int ch = (ks * 4 + lhi) ^ (row & 7);
        bvh[n] = *(const bf16x8*)((const char*)Bsh + row * 128 + ch * 16);
        bvl[n] = *(const bf16x8*)((const char*)Bsl + row * 128 + ch * 16);
      }
#pragma unroll
      for (int m = 0; m < 4; m++)
#pragma unroll
        for (int n = 0; n < 4; n++) {
          acc[m][n] = __builtin_amdgcn_mfma_f32_16x16x32_bf16(avh[m], bvl[n],
                                                              acc[m][n], 0, 0, 0);
          acc[m][n] = __builtin_amdgcn_mfma_f32_16x16x32_bf16(avl[m], bvh[n],
                                                              acc[m][n], 0, 0, 0);
          acc[m][n] = __builtin_amdgcn_mfma_f32_16x16x32_bf16(avh[m], bvh[n],
                                                              acc[m][n], 0, 0, 0);
        }
    }
    __syncthreads();
  }

  const int b_ = (int)(rA0 >> 11);
#pragma unroll
  for (int m = 0; m < 4; m++) {
#pragma unroll
    for (int n = 0; n < 4; n++) {
      const int col = (int)rB0 + wc * 64 + n * 16 + l16;
      const float bsv = bias[col];
      const int i = (col & 127) >> 1;
      const int hh = (col >> 7) & 15;
      const int d = col & 127;
#pragma unroll
      for (int r = 0; r < 4; r++) {
        const int row = (int)rA0 + wr * 64 + m * 16 + lhi * 4 + r;
        const int srow = row & 2047;
        const float v = acc[m][n][r] + bsv;
        const float p = __shfl_xor(v, 1);
        const float2 cs = rope[srow * 64 + i];
        const float o = ((lane & 1) == 0) ? (v * cs.x - p * cs.y)
                                          : (p * cs.y + v * cs.x);
        const unsigned short hi = f2bf(o);
        const unsigned short lo = f2bf(o - bf2f(hi));
        const long dst = ((long)(b_ * NH + hh) * SS + srow) * HD + d;
        if (col < 2048) { QH[dst] = hi; QL[dst] = lo; }
        else            { KH[dst] = hi; KL[dst] = lo; }
      }
    }
  }
}

// ---------------- V transpose: Vbf [m][2048] -> VT [bh][128][s] ------------
__global__ __launch_bounds__(256) void vtrans(
    const unsigned short* __restrict__ Vb, unsigned short* __restrict__ VTb) {
  __shared__ unsigned short t[32][33];
  const int bh = blockIdx.z, b = bh >> 4, h = bh & 15;
  const int d0 = blockIdx.x * 32, s0 = blockIdx.y * 32;
  const int tx = threadIdx.x, ty = threadIdx.y;
#pragma unroll
  for (int r = 0; r < 4; r++) {
    const int s = s0 + ty + r * 8;
    t[ty + r * 8][tx] = Vb[((long)(b * SS + s)) * HID + h * HD + d0 + tx];
  }
  __syncthreads();
#pragma unroll
  for (int r = 0; r < 4; r++) {
    const int d = d0 + ty + r * 8;
    VTb[((long)bh * HD + d) * SS + s0 + tx] = t[tx][ty + r * 8];
  }
}

// ---------------- 128x128-tile plain bf16 GEMM ----------------
template <int MODE>
__global__ __launch_bounds__(256) void gemm128(
    const unsigned short* __restrict__ A, const unsigned short* __restrict__ Bt,
    const float* __restrict__ bias, void* __restrict__ Cout, int M, int N,
    int K, const float* __restrict__ residF,
    const unsigned short* __restrict__ residB) {
  (void)M;
  __shared__ unsigned short As[128 * 64];
  __shared__ unsigned short Bs[128 * 64];
  const int tid = threadIdx.x;
  const int wid = tid >> 6, lane = tid & 63;
  const int l16 = lane & 15, lhi = lane >> 4;
  const int bn = blockIdx.x, bm = blockIdx.y;
  const int wr = wid >> 1, wc = wid & 1;
  const long rA0 = (long)bm * 128;
  const long rB0 = (long)bn * 128;

  f32x4 acc[4][4] = {};

  for (int kt = 0; kt < K; kt += 64) {
#pragma unroll
    for (int i = 0; i < 4; i++) {
      const int lin = i * 4096 + wid * 1024 + (lane << 4);
      const int row = lin >> 7;
      const int cs = ((lin >> 4) & 7) ^ (row & 7);
      gll16(A + (rA0 + row) * (long)K + kt + cs * 8,
            (const char*)As + (i * 4096 + wid * 1024));
      gll16(Bt + (rB0 + row) * (long)K + kt + cs * 8,
            (const char*)Bs + (i * 4096 + wid * 1024));
    }
    __syncthreads();
#pragma unroll
    for (int ks = 0; ks < 2; ks++) {
      bf16x8 av[4], bv[4];
#pragma unroll
      for (int m = 0; m < 4; m++) {
        const int row = wr * 64 + m * 16 + l16;
        const int ch = (ks * 4 + lhi) ^ (row & 7);
        av[m] = *(const bf16x8*)((const char*)As + row * 128 + ch * 16);
      }
#pragma unroll
      for (int n = 0; n < 4; n++) {
        const int row = wc * 64 + n * 16 + l16;
        const int ch = (ks * 4 + lhi) ^ (row & 7);
        bv[n] = *(const bf16x8*)((const char*)Bs + row * 128 + ch * 16);
      }
#pragma unroll
      for (int m = 0; m < 4; m++)
#pragma unroll
        for (int n = 0; n < 4; n++)
          acc[m][n] = __builtin_amdgcn_mfma_f32_16x16x32_bf16(av[m], bv[n],
                                                              acc[m][n], 0, 0, 0);
    }
    __syncthreads();
  }

#pragma unroll
  for (int m = 0; m < 4; m++) {
#pragma unroll
    for (int n = 0; n < 4; n++) {
      const long col = rB0 + wc * 64 + n * 16 + l16;
      const float bsv = bias[col];
#pragma unroll
      for (int r = 0; r < 4; r++) {
        const long row = rA0 + wr * 64 + m * 16 + lhi * 4 + r;
        float v = acc[m][n][r] + bsv;
        if (MODE == 1) v = 0.5f * v * (1.f + erff(v * 0.7071067811865475f));
        if (MODE == 2) {
          v += residF[row * N + col] + bf2f(residB[row * N + col]);
          ((float*)Cout)[row * N + col] = v;
        } else {
          ((unsigned short*)Cout)[row * N + col] = f2bf(v);
        }
      }
    }
  }
}

// -- flash v3: KVBLK=32, 2 blocks/CU, raw s_barrier + counted vmcnt ---------
// QH/QL/KH/KL: [bh][s][128]; VT: [bh][128][s]; AO: [b][s][h*128+d] bf16
__global__ __launch_bounds__(256, 2) void flash(
    const unsigned short* __restrict__ QH, const unsigned short* __restrict__ QL,
    const unsigned short* __restrict__ KH, const unsigned short* __restrict__ KL,
    const unsigned short* __restrict__ VT, const float* __restrict__ amask,
    unsigned short* __restrict__ AO) {
  __shared__ unsigned short Kth[2][32 * 128];  // 16KB [key][d] hi, dbuf
  __shared__ unsigned short Ktl[2][32 * 128];  // 16KB [key][d] lo, dbuf
  __shared__ unsigned short Vt[2][128 * 32];   // 16KB [d][key], dbuf
  __shared__ unsigned short Pl[4 * 1024];      //  8KB per-wave 32x32 P
  __shared__ float maskL[SS];                  //  8KB amask*log2e  => 64KB tot
  const int bh = blockIdx.y;
  // big+small qt pairing: co-resident blocks (c, c+256) get qt summing to 15
  const int qt = (bh >= 16) ? blockIdx.x : (15 - blockIdx.x);
  const int b = bh >> 4, h = bh & 15;
  const int tid = threadIdx.x, wid = tid >> 6, lane = tid & 63;
  const int l16 = lane & 15, lhi = lane >> 4;
  const unsigned short* Qhb = QH + (long)bh * SS * HD;
  const unsigned short* Qlb = QL + (long)bh * SS * HD;
  const unsigned short* Khb = KH + (long)bh * SS * HD;
  const unsigned short* Klb = KL + (long)bh * SS * HD;
  const unsigned short* Vb = VT + (long)bh * HD * SS;
  const int q0 = qt * 128 + wid * 32;
  const float LOG2E = 1.4426950408889634f;
  const float SCL2 = 16.322232154552f;  // sqrt(128)*log2e

  // amask row -> LDS (prescaled); keeps the K-loop free of global loads
  {
    const float4* mg = (const float4*)(amask + (long)b * SS);
    float4 m0 = mg[tid * 2], m1 = mg[tid * 2 + 1];
    m0.x *= LOG2E; m0.y *= LOG2E; m0.z *= LOG2E; m0.w *= LOG2E;
    m1.x *= LOG2E; m1.y *= LOG2E; m1.z *= LOG2E; m1.w *= LOG2E;
    ((float4*)maskL)[tid * 2] = m0;
    ((float4*)maskL)[tid * 2 + 1] = m1;
  }

  bf16x8 qfh[2][4], qfl[2][4];
#pragma unroll
  for (int mf = 0; mf < 2; mf++)
#pragma unroll
    for (int ks = 0; ks < 4; ks++) {
      const long o = (long)(q0 + mf * 16 + l16) * HD + ks * 32 + lhi * 8;
      qfh[mf][ks] = *(const bf16x8*)(Qhb + o);
      qfl[mf][ks] = *(const bf16x8*)(Qlb + o);
    }

  // stage tile kt2 (32 keys) into buffer bu: 6 loads/thread = 24KB/block
  auto stage = [&](int kt2, int bu) {
#pragma unroll
    for (int i = 0; i < 2; i++) {
      const int lin = i * 4096 + wid * 1024 + (lane << 4);
      const int dst = i * 4096 + wid * 1024;
      {
        const int row = lin >> 8;  // K rows are 256B (128 bf16)
        const int cs = ((lin >> 4) & 15) ^ (row & 7);
        const long g = (long)(kt2 * 32 + row) * HD + cs * 8;
        gll16(Khb + g, (const char*)Kth[bu] + dst);
        gll16(Klb + g, (const char*)Ktl[bu] + dst);
      }
      {
        const int row = lin >> 6;  // V rows are 64B (32 bf16 keys)
        const int cs = ((lin >> 4) & 3) ^ ((row >> 1) & 3);
        gll16(Vb + (long)row * SS + kt2 * 32 + cs * 8, (const char*)Vt[bu] + dst);
      }
    }
  };

  f32x4 accO[2][8] = {};
  float mrow[2][4], lrow[2][4];
#pragma unroll
  for (int mf = 0; mf < 2; mf++)
#pragma unroll
    for (int r = 0; r < 4; r++) { mrow[mf][r] = -3e38f; lrow[mf][r] = 0.f; }

  const int nkt = 4 * qt + 4;
  stage(0, 0);
  asm volatile("s_waitcnt lgkmcnt(0)" ::: "memory");  // maskL writes done
  int buf = 0;
  for (int kt = 0; kt < nkt; kt++) {
    if (kt + 1 < nkt) {
      stage(kt + 1, buf ^ 1);  // 6 loads stay in flight across the barrier
      asm volatile("s_waitcnt vmcnt(6)" ::: "memory");  // tile kt landed
    } else {
      asm volatile("s_waitcnt vmcnt(0)" ::: "memory");
    }
    __builtin_amdgcn_s_barrier();  // raw barrier: no vmcnt(0) drain

    // S = (Qh+Ql)(Kh+Kl)^T  (3-term split), 48 MFMAs
    f32x4 accS[2][2] = {};
    __builtin_amdgcn_s_setprio(1);
#pragma unroll
    for (int ks = 0; ks < 4; ks++) {
      bf16x8 bkh[2], bkl[2];
#pragma unroll
      for (int nf = 0; nf < 2; nf++) {
        const int row = nf * 16 + l16;
        const int ch = (ks * 4 + lhi) ^ (row & 7);
        bkh[nf] = *(const bf16x8*)((const char*)Kth[buf] + row * 256 + ch * 16);
        bkl[nf] = *(const bf16x8*)((const char*)Ktl[buf] + row * 256 + ch * 16);
      }
#pragma unroll
      for (int mf = 0; mf < 2; mf++)
#pragma unroll
        for (int nf = 0; nf < 2; nf++) {
          accS[mf][nf] = __builtin_amdgcn_mfma_f32_16x16x32_bf16(
              qfh[mf][ks], bkl[nf], accS[mf][nf], 0, 0, 0);
          accS[mf][nf] = __builtin_amdgcn_mfma_f32_16x16x32_bf16(
              qfl[mf][ks], bkh[nf], accS[mf][nf], 0, 0, 0);
          accS[mf][nf] = __builtin_amdgcn_mfma_f32_16x16x32_bf16(
              qfh[mf][ks], bkh[nf], accS[mf][nf], 0, 0, 0);
        }
    }
    __builtin_amdgcn_s_setprio(0);

    // scale to log2 domain + mask + causal
    float mk[2];
    mk[0] = maskL[kt * 32 + l16];
    mk[1] = maskL[kt * 32 + 16 + l16];
#pragma unroll
    for (int mf = 0; mf < 2; mf++)
#pragma unroll
      for (int nf = 0; nf < 2; nf++)
#pragma unroll
        for (int r = 0; r < 4; r++) {
          const int key = kt * 32 + nf * 16 + l16;
          const int qg = q0 + mf * 16 + lhi * 4 + r;
          const float sv = accS[mf][nf][r] * SCL2 + mk[nf];
          accS[mf][nf][r] = (key > qg) ? -1e30f : sv;
        }

    // row maxes
    float mx[2][4];
#pragma unroll
    for (int mf = 0; mf < 2; mf++)
#pragma unroll
      for (int r = 0; r < 4; r++) {
        float m0 = fmaxf(accS[mf][0][r], accS[mf][1][r]);
        m0 = fmaxf(m0, __shfl_xor(m0, 1));
        m0 = fmaxf(m0, __shfl_xor(m0, 2));
        m0 = fmaxf(m0, __shfl_xor(m0, 4));
        m0 = fmaxf(m0, __shfl_xor(m0, 8));
        mx[mf][r] = m0;
      }
    // defer-rescale: skip m-update + O-rescale when max grew by <= 8 (log2)
    bool defer = true;
#pragma unroll
    for (int mf = 0; mf < 2; mf++)
#pragma unroll
      for (int r = 0; r < 4; r++)
        defer = defer && (mx[mf][r] <= mrow[mf][r] + 8.f);
    if (!__all(defer)) {
#pragma unroll
      for (int mf = 0; mf < 2; mf++)
#pragma unroll
        for (int r = 0; r < 4; r++) {
          const float mnew = fmaxf(mrow[mf][r], mx[mf][r]);
          const float alpha = exp2f(mrow[mf][r] - mnew);
          mrow[mf][r] = mnew;
          lrow[mf][r] *= alpha;
#pragma unroll
          for (int nf2 = 0; nf2 < 8; nf2++) accO[mf][nf2][r] *= alpha;
        }
    }
    // P = exp2(S - m) -> per-wave LDS (32x32, 64B rows, swizzled)
#pragma unroll
    for (int mf = 0; mf < 2; mf++)
#pragma unroll
      for (int r = 0; r < 4; r++) {
        const int rowl = mf * 16 + lhi * 4 + r;
        const int qg = q0 + rowl;
        float rsum = 0.f;
#pragma unroll
        for (int nf = 0; nf < 2; nf++) {
          const int key = kt * 32 + nf * 16 + l16;
          const float p =
              (key > qg) ? 0.f : exp2f(accS[mf][nf][r] - mrow[mf][r]);
          rsum += p;
          const int colv = nf * 16 + l16;
          const int slot = (colv >> 3) ^ ((rowl >> 1) & 3);
          *(unsigned short*)((char*)Pl + wid * 2048 + rowl * 64 + slot * 16 +
                             (colv & 7) * 2) = f2bf(p);
        }
        rsum += __shfl_xor(rsum, 1);
        rsum += __shfl_xor(rsum, 2);
        rsum += __shfl_xor(rsum, 4);
        rsum += __shfl_xor(rsum, 8);
        lrow[mf][r] += rsum;
      }

    // O += P V  (16 MFMAs)
    __builtin_amdgcn_s_setprio(1);
    {
      bf16x8 pa[2];
#pragma unroll
      for (int mf = 0; mf < 2; mf++) {
        const int rowp = mf * 16 + l16;
        const int ch = lhi ^ ((rowp >> 1) & 3);
        pa[mf] = *(const bf16x8*)((const char*)Pl + wid * 2048 + rowp * 64 +
                                  ch * 16);
      }
#pragma unroll
      for (int nf2 = 0; nf2 < 8; nf2++) {
        const int rowv = nf2 * 16 + l16;
        const int ch = lhi ^ ((rowv >> 1) & 3);
        bf16x8 vv =
            *(const bf16x8*)((const char*)Vt[buf] + rowv * 64 + ch * 16);
#pragma unroll
        for (int mf = 0; mf < 2; mf++)
          accO[mf][nf2] = __builtin_amdgcn_mfma_f32_16x16x32_bf16(
              pa[mf], vv, accO[mf][nf2], 0, 0, 0);
      }
    }
    __builtin_amdgcn_s_setprio(0);
    __builtin_amdgcn_s_barrier();  // all waves done with buf before restage
    buf ^= 1;
  }

#pragma unroll
  for (int mf = 0; mf < 2; mf++)
#pragma unroll
    for (int nf2 = 0; nf2 < 8; nf2++)
#pragma unroll
      for (int r = 0; r < 4; r++) {
        const int qg = q0 + mf * 16 + lhi * 4 + r;
        const int d = nf2 * 16 + l16;
        const float v = accO[mf][nf2][r] / lrow[mf][r];
        AO[((long)(b * SS + qg)) * HID + h * HD + d] = f2bf(v);
      }
}

extern "C" void kernel_launch(void* const* d_in, const int* in_sizes, int n_in,
                              void* d_out, int out_size, void* d_ws,
                              size_t ws_size, hipStream_t stream) {
  (void)in_sizes; (void)n_in; (void)out_size;
  const float* hidden = (const float*)d_in[0];
  const float* amask = (const float*)d_in[1];
  const float* w_qkv = (const float*)d_in[2];
  const float* b_qkv = (const float*)d_in[3];
  const float* w_o = (const float*)d_in[4];
  const float* b_o = (const float*)d_in[5];
  const float* ln1s = (const float*)d_in[6];
  const float* ln1b = (const float*)d_in[7];
  const float* ln2s = (const float*)d_in[8];
  const float* ln2b = (const float*)d_in[9];
  const float* w_in = (const float*)d_in[10];
  const float* b_in = (const float*)d_in[11];
  const float* w_out = (const float*)d_in[12];
  const float* b_out = (const float*)d_in[13];

  char* ws = (char*)d_ws;
  // liveness-aliased workspace (194 MB total; 219 MB known available)
  unsigned short* X1h = (unsigned short*)(ws + 0);           // 16MB, later AO
  unsigned short* X1l = (unsigned short*)(ws + 16777216);    // 16MB, later Vbf
  unsigned short* X2  = (unsigned short*)(ws + 33554432);    // 16MB
  unsigned short* W1h = (unsigned short*)(ws + 50331648);    // 16MB, later Win/Wout
  unsigned short* W1l = (unsigned short*)(ws + 67108864);    // 16MB, later Win/Wout
  unsigned short* WE  = (unsigned short*)(ws + 83886080);    // 8MB: Wv then Wo
  unsigned short* QHb = (unsigned short*)(ws + 92274688);    // 16MB, later H1
  unsigned short* QLb = (unsigned short*)(ws + 109051904);   // 16MB, later H1
  unsigned short* KHb = (unsigned short*)(ws + 125829120);   // 16MB, later H1
  unsigned short* KLb = (unsigned short*)(ws + 142606336);   // 16MB, later H1
  unsigned short* VTb = (unsigned short*)(ws + 159383552);   // 16MB
  unsigned short* ATT = (unsigned short*)(ws + 176160768);   // 16MB
  float2* ROPE = (float2*)(ws + 192937984);                  // 1MB
  if (ws_size < 193986560) return;

  unsigned short* Vbf = X1l;   // x1-lo dead after gemmqk
  unsigned short* AO = X1h;    // x1-hi dead after v-gemm
  unsigned short* WD = W1h;    // 32MB region reused for Win^T / Wout^T
  unsigned short* H1 = QHb;    // 64MB region reused after flash

  ln2k<<<MT, 256, 0, stream>>>(hidden, ln1s, ln1b, ln2s, ln2b, X1h, X1l, X2);
  rope_tab<<<SS, 64, 0, stream>>>(ROPE);
  // q,k: split-precision GEMM + fused rope
  wtrans_hl<<<dim3(128, 64), dim3(32, 8), 0, stream>>>(w_qkv, W1h, W1l,
                                                       HID, 3 * HID);
  gemmqk<<<dim3(32, 32), 256, 0, stream>>>(X1h, X1l, W1h, W1l, b_qkv, ROPE,
                                           QHb, QLb, KHb, KLb);
  // v: plain bf16 GEMM
  wtrans<<<dim3(64, 64), dim3(32, 8), 0, stream>>>(w_qkv, WE, HID, HID,
                                                   3 * HID, 2 * HID);
  gemm128<0><<<dim3(16, 32), 256, 0, stream>>>(X1h, WE, b_qkv + 2 * HID, Vbf,
                                               MT, HID, HID, nullptr, nullptr);
  vtrans<<<dim3(4, 64, 32), dim3(32, 8), 0, stream>>>(Vbf, VTb);
  flash<<<dim3(16, 32), 256, 0, stream>>>(QHb, QLb, KHb, KLb, VTb, amask, AO);
  // attention projection
  wtrans<<<dim3(64, 64), dim3(32, 8), 0, stream>>>(w_o, WE, HID, HID, HID, 0);
  gemm128<0><<<dim3(16, 32), 256, 0, stream>>>(AO, WE, b_o, ATT, MT, HID, HID,
                                               nullptr, nullptr);
  // mlp
  wtrans<<<dim3(256, 64), dim3(32, 8), 0, stream>>>(w_in, WD, HID, INTER,
                                                    INTER, 0);
  gemm128<1><<<dim3(64, 32), 256, 0, stream>>>(X2, WD, b_in, H1, MT, INTER,
                                               HID, nullptr, nullptr);
  wtrans<<<dim3(64, 256), dim3(32, 8), 0, stream>>>(w_out, WD, INTER, HID,
                                                    HID, 0);
  gemm128<2><<<dim3(16, 32), 256, 0, stream>>>(H1, WD, b_out, d_out, MT, HID,
                                               INTER, hidden, ATT);
}